// Round 2
// baseline (1057.526 us; speedup 1.0000x reference)
//
#include <hip/hip_runtime.h>
#include <math.h>

#define NROWS 131072   // 32*64*64
#define CDIM  64
#define NCODE 1024

__global__ void vq_zero_loss(float* loss) { *loss = 0.0f; }

// Block = 256 threads = 4 waves. Block covers 64 rows; wave w scans codebook
// chunk [w*256, w*256+256) for all 64 rows (one row per lane). Chunk pointer
// stays wave-uniform -> scalar loads. Partials combined via LDS.
__global__ __launch_bounds__(256) void vq_main(
    const float* __restrict__ ze, const float* __restrict__ embs,
    float* __restrict__ out, float* __restrict__ loss)
{
    __shared__ float s_e2[NCODE];
    __shared__ float s_best[4][64];
    __shared__ int   s_bidx[4][64];
    __shared__ float s_red[4];
    const int tid = threadIdx.x;

    // --- codebook squared norms -> LDS (each block computes its own copy) ---
    #pragma unroll
    for (int j = 0; j < 4; ++j) {
        const int k = tid + 256 * j;
        const float* ep = embs + (size_t)k * CDIM;
        float s = 0.0f;
        #pragma unroll
        for (int d = 0; d < CDIM; d += 4) {
            const float4 e4 = *(const float4*)(ep + d);
            s = fmaf(e4.x, e4.x, s);
            s = fmaf(e4.y, e4.y, s);
            s = fmaf(e4.z, e4.z, s);
            s = fmaf(e4.w, e4.w, s);
        }
        s_e2[k] = s;
    }
    __syncthreads();

    const int wv   = tid >> 6;   // wave index in block = codebook chunk (uniform)
    const int lane = tid & 63;
    const int row  = blockIdx.x * 64 + lane;

    // --- load this lane's row into registers ---
    const float* zp = ze + (size_t)row * CDIM;
    float z[CDIM];
    #pragma unroll
    for (int d = 0; d < CDIM; d += 4) {
        const float4 v = *(const float4*)(zp + d);
        z[d + 0] = v.x; z[d + 1] = v.y; z[d + 2] = v.z; z[d + 3] = v.w;
    }

    // --- partial argmin over this wave's chunk: dist = ||e||^2 - 2 z.e ---
    float best = INFINITY;
    int bidx = 0;
    const int k0 = wv * (NCODE / 4);
    for (int kk = 0; kk < NCODE / 4; ++kk) {
        const int k = k0 + kk;
        const float* __restrict__ ep = embs + (size_t)k * CDIM;  // wave-uniform -> s_load
        float a0 = 0.0f, a1 = 0.0f, a2 = 0.0f, a3 = 0.0f;
        #pragma unroll
        for (int d = 0; d < CDIM; d += 4) {
            a0 = fmaf(z[d + 0], ep[d + 0], a0);
            a1 = fmaf(z[d + 1], ep[d + 1], a1);
            a2 = fmaf(z[d + 2], ep[d + 2], a2);
            a3 = fmaf(z[d + 3], ep[d + 3], a3);
        }
        const float dist = s_e2[k] - 2.0f * ((a0 + a1) + (a2 + a3));
        if (dist < best) { best = dist; bidx = k; }   // strict < : first-min in chunk
    }
    s_best[wv][lane] = best;
    s_bidx[wv][lane] = bidx;
    __syncthreads();

    // --- combine 4 chunk-partials; thread covers row rl=tid>>2, dims q*16.. ---
    const int rl = tid >> 2;
    const int q  = tid & 3;
    float wbest = s_best[0][rl];
    int   wbidx = s_bidx[0][rl];
    #pragma unroll
    for (int j = 1; j < 4; ++j) {
        const float dj = s_best[j][rl];
        const int   ij = s_bidx[j][rl];
        if (dj < wbest || (dj == wbest && ij < wbidx)) { wbest = dj; wbidx = ij; }
    }

    // --- gather winner slice, write zq, accumulate (zq - ze)^2 (coalesced) ---
    const size_t obase = (size_t)(blockIdx.x * 64 + rl) * CDIM + q * 16;
    const float* ep = embs + (size_t)wbidx * CDIM + q * 16;
    const float* zr = ze + obase;     // L1/L2-hot re-read (avoids dynamic reg indexing)
    float* op = out + obase;
    float psum = 0.0f;
    #pragma unroll
    for (int d = 0; d < 16; d += 4) {
        const float4 e4 = *(const float4*)(ep + d);
        *(float4*)(op + d) = e4;
        const float4 zv = *(const float4*)(zr + d);
        const float d0 = e4.x - zv.x;
        const float d1 = e4.y - zv.y;
        const float d2 = e4.z - zv.z;
        const float d3 = e4.w - zv.w;
        psum = fmaf(d0, d0, psum);
        psum = fmaf(d1, d1, psum);
        psum = fmaf(d2, d2, psum);
        psum = fmaf(d3, d3, psum);
    }

    // --- loss reduction: wave shuffle -> LDS -> one atomic per block ---
    #pragma unroll
    for (int off = 32; off > 0; off >>= 1)
        psum += __shfl_down(psum, off, 64);
    if (lane == 0) s_red[wv] = psum;
    __syncthreads();
    if (tid == 0) {
        const float b = (s_red[0] + s_red[1]) + (s_red[2] + s_red[3]);
        atomicAdd(loss, b * (1.25f / ((float)NROWS * (float)CDIM)));
    }
}

extern "C" void kernel_launch(void* const* d_in, const int* in_sizes, int n_in,
                              void* d_out, int out_size, void* d_ws, size_t ws_size,
                              hipStream_t stream) {
    const float* ze   = (const float*)d_in[0];   // [32,64,64,64] fp32
    const float* embs = (const float*)d_in[1];   // [1024,64] fp32
    float* out  = (float*)d_out;                 // zq_st (8388608 floats) then loss (1)
    float* loss = out + (out_size - 1);

    vq_zero_loss<<<1, 1, 0, stream>>>(loss);
    vq_main<<<NROWS / 64, 256, 0, stream>>>(ze, embs, out, loss);
}

// Round 3
// 382.272 us; speedup vs baseline: 2.7664x; 2.7664x over previous
//
#include <hip/hip_runtime.h>
#include <math.h>

#define NROWS 131072   // 32*64*64
#define CDIM  64
#define NCODE 1024

__global__ void vq_zero_loss(float* loss) { *loss = 0.0f; }

// Precompute codebook squared norms -> d_ws (1024 floats), once per launch.
__global__ __launch_bounds__(256) void vq_prep(
    const float* __restrict__ embs, float* __restrict__ e2)
{
    const int k = blockIdx.x * 256 + threadIdx.x;
    const float* ep = embs + (size_t)k * CDIM;
    float s = 0.0f;
    #pragma unroll
    for (int d = 0; d < CDIM; d += 4) {
        const float4 e4 = *(const float4*)(ep + d);
        s = fmaf(e4.x, e4.x, s);
        s = fmaf(e4.y, e4.y, s);
        s = fmaf(e4.z, e4.z, s);
        s = fmaf(e4.w, e4.w, s);
    }
    e2[k] = s;
}

// Block = 256 threads = 4 waves covering 64 rows; wave w scans codebook chunk
// [w*256, w*256+256) for all 64 rows (one row per lane). The chunk base is
// forced uniform via readfirstlane so codebook reads compile to s_load and
// feed v_fma's SGPR operand (round-1-proven path). Partials combine via LDS.
__global__ __launch_bounds__(256) void vq_main(
    const float* __restrict__ ze, const float* __restrict__ embs,
    const float* __restrict__ e2, float* __restrict__ out,
    float* __restrict__ loss)
{
    __shared__ float s_best[4][64];
    __shared__ int   s_bidx[4][64];
    __shared__ float s_red[4];
    const int tid  = threadIdx.x;
    const int lane = tid & 63;
    // wave index in block — runtime-uniform; readfirstlane makes it an SGPR
    const int wv = __builtin_amdgcn_readfirstlane(tid >> 6);
    const int row = blockIdx.x * 64 + lane;

    // --- load this lane's row, pre-scaled by -2 (dist = ||e||^2 - 2 z.e) ---
    const float* zp = ze + (size_t)row * CDIM;
    float z2[CDIM];
    #pragma unroll
    for (int d = 0; d < CDIM; d += 4) {
        const float4 v = *(const float4*)(zp + d);
        z2[d + 0] = -2.0f * v.x; z2[d + 1] = -2.0f * v.y;
        z2[d + 2] = -2.0f * v.z; z2[d + 3] = -2.0f * v.w;
    }

    // --- partial argmin over this wave's chunk ---
    float best = INFINITY;
    int bidx = 0;
    const int k0 = wv * (NCODE / 4);
    #pragma unroll 2
    for (int kk = 0; kk < NCODE / 4; ++kk) {
        const int k = k0 + kk;                                   // uniform (SGPR)
        const float* __restrict__ ep = embs + (size_t)k * CDIM;  // -> s_load
        float a0 = e2[k];                                        // -> s_load
        float a1 = 0.0f, a2 = 0.0f, a3 = 0.0f;
        #pragma unroll
        for (int d = 0; d < CDIM; d += 4) {
            a0 = fmaf(z2[d + 0], ep[d + 0], a0);
            a1 = fmaf(z2[d + 1], ep[d + 1], a1);
            a2 = fmaf(z2[d + 2], ep[d + 2], a2);
            a3 = fmaf(z2[d + 3], ep[d + 3], a3);
        }
        const float dist = (a0 + a1) + (a2 + a3);
        if (dist < best) { best = dist; bidx = k; }   // strict < : first-min in chunk
    }
    s_best[wv][lane] = best;
    s_bidx[wv][lane] = bidx;
    __syncthreads();

    // --- combine 4 chunk-partials; thread covers row rl=tid>>2, dims q*16.. ---
    const int rl = tid >> 2;
    const int q  = tid & 3;
    float wbest = s_best[0][rl];
    int   wbidx = s_bidx[0][rl];
    #pragma unroll
    for (int j = 1; j < 4; ++j) {
        const float dj = s_best[j][rl];
        const int   ij = s_bidx[j][rl];
        if (dj < wbest || (dj == wbest && ij < wbidx)) { wbest = dj; wbidx = ij; }
    }

    // --- gather winner slice, write zq, accumulate (zq - ze)^2 (coalesced) ---
    const size_t obase = (size_t)(blockIdx.x * 64 + rl) * CDIM + q * 16;
    const float* ep = embs + (size_t)wbidx * CDIM + q * 16;
    const float* zr = ze + obase;     // L1/L2-hot re-read
    float* op = out + obase;
    float psum = 0.0f;
    #pragma unroll
    for (int d = 0; d < 16; d += 4) {
        const float4 e4 = *(const float4*)(ep + d);
        *(float4*)(op + d) = e4;
        const float4 zv = *(const float4*)(zr + d);
        const float d0 = e4.x - zv.x;
        const float d1 = e4.y - zv.y;
        const float d2 = e4.z - zv.z;
        const float d3 = e4.w - zv.w;
        psum = fmaf(d0, d0, psum);
        psum = fmaf(d1, d1, psum);
        psum = fmaf(d2, d2, psum);
        psum = fmaf(d3, d3, psum);
    }

    // --- loss reduction: wave shuffle -> LDS -> one atomic per block ---
    #pragma unroll
    for (int off = 32; off > 0; off >>= 1)
        psum += __shfl_down(psum, off, 64);
    if (lane == 0) s_red[tid >> 6] = psum;
    __syncthreads();
    if (tid == 0) {
        const float b = (s_red[0] + s_red[1]) + (s_red[2] + s_red[3]);
        atomicAdd(loss, b * (1.25f / ((float)NROWS * (float)CDIM)));
    }
}

extern "C" void kernel_launch(void* const* d_in, const int* in_sizes, int n_in,
                              void* d_out, int out_size, void* d_ws, size_t ws_size,
                              hipStream_t stream) {
    const float* ze   = (const float*)d_in[0];   // [32,64,64,64] fp32
    const float* embs = (const float*)d_in[1];   // [1024,64] fp32
    float* out  = (float*)d_out;                 // zq_st (8388608 floats) then loss (1)
    float* loss = out + (out_size - 1);
    float* e2   = (float*)d_ws;                  // 1024 floats scratch

    vq_zero_loss<<<1, 1, 0, stream>>>(loss);
    vq_prep<<<NCODE / 256, 256, 0, stream>>>(embs, e2);
    vq_main<<<NROWS / 64, 256, 0, stream>>>(ze, embs, e2, out, loss);
}

// Round 4
// 297.523 us; speedup vs baseline: 3.5544x; 1.2848x over previous
//
#include <hip/hip_runtime.h>
#include <math.h>

#define NROWS 131072   // 32*64*64
#define CDIM  64
#define NCODE 1024

__global__ void vq_zero_loss(float* loss) { *loss = 0.0f; }

// Precompute codebook squared norms -> d_ws (1024 floats).
__global__ __launch_bounds__(256) void vq_prep(
    const float* __restrict__ embs, float* __restrict__ e2)
{
    const int k = blockIdx.x * 256 + threadIdx.x;
    const float* ep = embs + (size_t)k * CDIM;
    float s = 0.0f;
    #pragma unroll
    for (int d = 0; d < CDIM; d += 4) {
        const float4 e4 = *(const float4*)(ep + d);
        s = fmaf(e4.x, e4.x, s);
        s = fmaf(e4.y, e4.y, s);
        s = fmaf(e4.z, e4.z, s);
        s = fmaf(e4.w, e4.w, s);
    }
    e2[k] = s;
}

// Block = 4 waves, 128 rows (2 rows per lane, R=2 register blocking).
// Wave w scans codebook chunk [w*256, w*256+256) for its 128 rows; chunk
// base forced uniform via readfirstlane -> codebook stays on the scalar
// (s_load) path, and each loaded code row now feeds 128 FMAs instead of 64,
// halving the exposed SMEM latency per FMA.
__global__ __launch_bounds__(256) void vq_main(
    const float* __restrict__ ze, const float* __restrict__ embs,
    const float* __restrict__ e2, float* __restrict__ out,
    float* __restrict__ loss)
{
    __shared__ float s_best[4][128];
    __shared__ int   s_bidx[4][128];
    __shared__ float s_red[4];
    const int tid  = threadIdx.x;
    const int lane = tid & 63;
    const int wv = __builtin_amdgcn_readfirstlane(tid >> 6);  // uniform chunk id

    // --- load 2 rows per lane, pre-scaled by -2 (dist = ||e||^2 - 2 z.e) ---
    const int rbase = blockIdx.x * 128;
    float z2[2][CDIM];
    #pragma unroll
    for (int r = 0; r < 2; ++r) {
        const float* zp = ze + (size_t)(rbase + r * 64 + lane) * CDIM;
        #pragma unroll
        for (int d = 0; d < CDIM; d += 4) {
            const float4 v = *(const float4*)(zp + d);
            z2[r][d + 0] = -2.0f * v.x; z2[r][d + 1] = -2.0f * v.y;
            z2[r][d + 2] = -2.0f * v.z; z2[r][d + 3] = -2.0f * v.w;
        }
    }

    // --- partial argmin over this wave's chunk, both rows ---
    float best0 = INFINITY, best1 = INFINITY;
    int bidx0 = 0, bidx1 = 0;
    const int k0 = wv * (NCODE / 4);
    #pragma unroll 1
    for (int kk = 0; kk < NCODE / 4; ++kk) {
        const int k = k0 + kk;                                   // uniform (SGPR)
        const float* __restrict__ ep = embs + (size_t)k * CDIM;  // -> s_load
        const float ek = e2[k];                                  // -> s_load
        float a0 = ek, a1 = 0.0f, a2 = 0.0f, a3 = 0.0f;
        float b0 = ek, b1 = 0.0f, b2 = 0.0f, b3 = 0.0f;
        #pragma unroll
        for (int d = 0; d < CDIM; d += 4) {
            const float c0 = ep[d + 0], c1 = ep[d + 1];
            const float c2 = ep[d + 2], c3 = ep[d + 3];
            a0 = fmaf(z2[0][d + 0], c0, a0);
            a1 = fmaf(z2[0][d + 1], c1, a1);
            a2 = fmaf(z2[0][d + 2], c2, a2);
            a3 = fmaf(z2[0][d + 3], c3, a3);
            b0 = fmaf(z2[1][d + 0], c0, b0);
            b1 = fmaf(z2[1][d + 1], c1, b1);
            b2 = fmaf(z2[1][d + 2], c2, b2);
            b3 = fmaf(z2[1][d + 3], c3, b3);
        }
        const float d0 = (a0 + a1) + (a2 + a3);
        const float d1 = (b0 + b1) + (b2 + b3);
        if (d0 < best0) { best0 = d0; bidx0 = k; }   // strict < : first-min in chunk
        if (d1 < best1) { best1 = d1; bidx1 = k; }
    }
    s_best[wv][lane]      = best0;
    s_bidx[wv][lane]      = bidx0;
    s_best[wv][64 + lane] = best1;
    s_bidx[wv][64 + lane] = bidx1;
    __syncthreads();

    // --- combine 4 chunk-partials + epilogue, two 64-row halves ---
    float psum = 0.0f;
    const int rl = tid >> 2;   // row within half
    const int q  = tid & 3;    // 16-float slice
    #pragma unroll
    for (int h = 0; h < 2; ++h) {
        const int rr = h * 64 + rl;
        float wbest = s_best[0][rr];
        int   wbidx = s_bidx[0][rr];
        #pragma unroll
        for (int j = 1; j < 4; ++j) {
            const float dj = s_best[j][rr];
            const int   ij = s_bidx[j][rr];
            if (dj < wbest || (dj == wbest && ij < wbidx)) { wbest = dj; wbidx = ij; }
        }
        const size_t obase = (size_t)(rbase + rr) * CDIM + q * 16;
        const float* ep = embs + (size_t)wbidx * CDIM + q * 16;
        const float* zr = ze + obase;     // L1/L2-hot re-read
        float* op = out + obase;
        #pragma unroll
        for (int d = 0; d < 16; d += 4) {
            const float4 e4 = *(const float4*)(ep + d);
            *(float4*)(op + d) = e4;
            const float4 zv = *(const float4*)(zr + d);
            const float f0 = e4.x - zv.x;
            const float f1 = e4.y - zv.y;
            const float f2 = e4.z - zv.z;
            const float f3 = e4.w - zv.w;
            psum = fmaf(f0, f0, psum);
            psum = fmaf(f1, f1, psum);
            psum = fmaf(f2, f2, psum);
            psum = fmaf(f3, f3, psum);
        }
    }

    // --- loss reduction: wave shuffle -> LDS -> one atomic per block ---
    #pragma unroll
    for (int off = 32; off > 0; off >>= 1)
        psum += __shfl_down(psum, off, 64);
    if (lane == 0) s_red[tid >> 6] = psum;
    __syncthreads();
    if (tid == 0) {
        const float b = (s_red[0] + s_red[1]) + (s_red[2] + s_red[3]);
        atomicAdd(loss, b * (1.25f / ((float)NROWS * (float)CDIM)));
    }
}

extern "C" void kernel_launch(void* const* d_in, const int* in_sizes, int n_in,
                              void* d_out, int out_size, void* d_ws, size_t ws_size,
                              hipStream_t stream) {
    const float* ze   = (const float*)d_in[0];   // [32,64,64,64] fp32
    const float* embs = (const float*)d_in[1];   // [1024,64] fp32
    float* out  = (float*)d_out;                 // zq_st (8388608 floats) then loss (1)
    float* loss = out + (out_size - 1);
    float* e2   = (float*)d_ws;                  // 1024 floats scratch

    vq_zero_loss<<<1, 1, 0, stream>>>(loss);
    vq_prep<<<NCODE / 256, 256, 0, stream>>>(embs, e2);
    vq_main<<<NROWS / 128, 256, 0, stream>>>(ze, embs, e2, out, loss);
}

// Round 5
// 239.378 us; speedup vs baseline: 4.4178x; 1.2429x over previous
//
#include <hip/hip_runtime.h>
#include <math.h>

#define NROWS 131072   // 32*64*64
#define CDIM  64
#define NCODE 1024
#define NT    (NCODE / 16)
#define MARGIN 0.0625f
#define LOSS_SCALE (1.25f / ((float)NROWS * (float)CDIM))

typedef _Float16 half8 __attribute__((ext_vector_type(8)));
typedef _Float16 half4 __attribute__((ext_vector_type(4)));
typedef float    f32x4 __attribute__((ext_vector_type(4)));

// d_ws layout (bytes):
//   [0, 4096)        e2   : fp32[1024] codebook squared norms
//   [4096, 135168)   eh   : f16[1024*64] codebook (RTNE)
//   [135168, 135172) cnt  : u32 uncertain-row counter
//   [135424, ...)    list : u32[] packed (row<<10 | idx)
#define WS_EH_OFF   4096
#define WS_CNT_OFF  135168
#define WS_LIST_OFF 135424

__global__ void vq_zero(float* loss, unsigned* cnt) { *loss = 0.0f; *cnt = 0u; }

// One thread per code: squared norm (fp32) + f16 conversion of the row.
__global__ __launch_bounds__(256) void vq_prep(
    const float* __restrict__ embs, float* __restrict__ e2,
    unsigned short* __restrict__ eh_u)
{
    _Float16* eh = (_Float16*)eh_u;
    const int k = blockIdx.x * 256 + threadIdx.x;
    const float* ep = embs + (size_t)k * CDIM;
    float s = 0.0f;
    #pragma unroll
    for (int d = 0; d < CDIM; d += 4) {
        const float4 e4 = *(const float4*)(ep + d);
        s = fmaf(e4.x, e4.x, s);
        s = fmaf(e4.y, e4.y, s);
        s = fmaf(e4.z, e4.z, s);
        s = fmaf(e4.w, e4.w, s);
        half4 h;
        h[0] = (_Float16)e4.x; h[1] = (_Float16)e4.y;
        h[2] = (_Float16)e4.z; h[3] = (_Float16)e4.w;
        *(half4*)(eh + (size_t)k * CDIM + d) = h;
    }
    e2[k] = s;
}

// Pass 1: MFMA screening. Block = 4 waves; wave covers 32 rows (2 16-row
// M-tiles). dist(m,n) = e2[n] + (-2 z_m).eh_n, computed as f16 MFMA with a
// 2-term hi/lo split of A (so z.eh is near-exact; residual err = z.(e-eh),
// RMS ~2.5e-3). Tracks best + second-best per row; rows with gap < MARGIN
// go to a recheck list resolved exactly in fp32 by pass 2.
__global__ __launch_bounds__(256) void vq_pass1(
    const float* __restrict__ ze, const float* __restrict__ embs,
    const float* __restrict__ e2, const unsigned short* __restrict__ eh_u,
    float* __restrict__ out, float* __restrict__ loss,
    unsigned* __restrict__ cnt, unsigned* __restrict__ list, int listcap)
{
    const _Float16* eh = (const _Float16*)eh_u;
    __shared__ unsigned s_idx[128];
    __shared__ float s_red[4];
    const int tid  = threadIdx.x;
    const int lane = tid & 63;
    const int wv   = tid >> 6;
    const int col  = lane & 15;   // N (code) within tile; also M row for A-frag
    const int quad = lane >> 4;
    const int rbase = blockIdx.x * 128 + wv * 32;

    // --- A fragments: hi/lo f16 split of -2z. A[m][k]: m=lane&15, k=quad*8+j.
    half8 ah[2][2], al[2][2];   // [tile][khalf]
    #pragma unroll
    for (int t = 0; t < 2; ++t) {
        const float* zp = ze + (size_t)(rbase + t * 16 + col) * CDIM + quad * 8;
        #pragma unroll
        for (int h = 0; h < 2; ++h) {
            const float4 v0 = *(const float4*)(zp + h * 32);
            const float4 v1 = *(const float4*)(zp + h * 32 + 4);
            const float m[8] = {-2.0f * v0.x, -2.0f * v0.y, -2.0f * v0.z, -2.0f * v0.w,
                                -2.0f * v1.x, -2.0f * v1.y, -2.0f * v1.z, -2.0f * v1.w};
            #pragma unroll
            for (int j = 0; j < 8; ++j) {
                const _Float16 hi = (_Float16)m[j];
                ah[t][h][j] = hi;
                al[t][h][j] = (_Float16)(m[j] - (float)hi);
            }
        }
    }

    // --- running best / second-best / best-ntile per C/D reg (row) ---
    float bb[2][4], ss[2][4];
    int   tt[2][4];
    #pragma unroll
    for (int t = 0; t < 2; ++t)
        #pragma unroll
        for (int r = 0; r < 4; ++r) { bb[t][r] = INFINITY; ss[t][r] = INFINITY; tt[t][r] = 0; }

    const _Float16* ehc = eh + (size_t)col * CDIM + quad * 8;  // B[k][n]: n=col, k=quad*8+j
    #pragma unroll 2
    for (int nt = 0; nt < NT; ++nt) {
        const float ev = e2[nt * 16 + col];
        const half8 b0 = *(const half8*)(ehc + (size_t)nt * 16 * CDIM);
        const half8 b1 = *(const half8*)(ehc + (size_t)nt * 16 * CDIM + 32);
        f32x4 a0 = {ev, ev, ev, ev};
        f32x4 a1 = {ev, ev, ev, ev};
        a0 = __builtin_amdgcn_mfma_f32_16x16x32_f16(ah[0][0], b0, a0, 0, 0, 0);
        a1 = __builtin_amdgcn_mfma_f32_16x16x32_f16(ah[1][0], b0, a1, 0, 0, 0);
        a0 = __builtin_amdgcn_mfma_f32_16x16x32_f16(al[0][0], b0, a0, 0, 0, 0);
        a1 = __builtin_amdgcn_mfma_f32_16x16x32_f16(al[1][0], b0, a1, 0, 0, 0);
        a0 = __builtin_amdgcn_mfma_f32_16x16x32_f16(ah[0][1], b1, a0, 0, 0, 0);
        a1 = __builtin_amdgcn_mfma_f32_16x16x32_f16(ah[1][1], b1, a1, 0, 0, 0);
        a0 = __builtin_amdgcn_mfma_f32_16x16x32_f16(al[0][1], b1, a0, 0, 0, 0);
        a1 = __builtin_amdgcn_mfma_f32_16x16x32_f16(al[1][1], b1, a1, 0, 0, 0);
        #pragma unroll
        for (int r = 0; r < 4; ++r) {
            const float u0 = a0[r];
            ss[0][r] = fminf(ss[0][r], fmaxf(bb[0][r], u0));
            tt[0][r] = (u0 < bb[0][r]) ? nt : tt[0][r];
            bb[0][r] = fminf(bb[0][r], u0);
            const float u1 = a1[r];
            ss[1][r] = fminf(ss[1][r], fmaxf(bb[1][r], u1));
            tt[1][r] = (u1 < bb[1][r]) ? nt : tt[1][r];
            bb[1][r] = fminf(bb[1][r], u1);
        }
    }

    // --- cross-lane (16 cols) argmin+second reduce; C/D row m = quad*4+r ---
    #pragma unroll
    for (int t = 0; t < 2; ++t) {
        #pragma unroll
        for (int r = 0; r < 4; ++r) {
            float b = bb[t][r], s = ss[t][r];
            int   i = tt[t][r] * 16 + col;
            #pragma unroll
            for (int off = 1; off < 16; off <<= 1) {
                const float ob = __shfl_xor(b, off, 64);
                const float os = __shfl_xor(s, off, 64);
                const int   oi = __shfl_xor(i, off, 64);
                s = fminf(fminf(s, os), fmaxf(b, ob));  // second = min(seconds, loser-best)
                const bool take = (ob < b) || (ob == b && oi < i);
                b = take ? ob : b;
                i = take ? oi : i;
            }
            if (col == 0) {
                const int lrow = wv * 32 + t * 16 + quad * 4 + r;
                s_idx[lrow] = (unsigned)i;
                if (s - b < MARGIN) {
                    const unsigned p = atomicAdd(cnt, 1u);
                    if ((int)p < listcap)
                        list[p] = ((unsigned)(blockIdx.x * 128 + lrow) << 10) | (unsigned)i;
                }
            }
        }
    }
    __syncthreads();

    // --- epilogue: thread covers row tid>>1, 32-dim half tid&1 (coalesced) ---
    const int rr = tid >> 1;
    const int hh = tid & 1;
    const unsigned widx = s_idx[rr];
    const size_t obase = (size_t)(blockIdx.x * 128 + rr) * CDIM + hh * 32;
    const float* ep = embs + (size_t)widx * CDIM + hh * 32;
    const float* zr = ze + obase;    // L1/L2-hot re-read
    float* op = out + obase;
    float psum = 0.0f;
    #pragma unroll
    for (int d = 0; d < 32; d += 4) {
        const float4 e4 = *(const float4*)(ep + d);
        *(float4*)(op + d) = e4;
        const float4 zv = *(const float4*)(zr + d);
        const float f0 = e4.x - zv.x;
        const float f1 = e4.y - zv.y;
        const float f2 = e4.z - zv.z;
        const float f3 = e4.w - zv.w;
        psum = fmaf(f0, f0, psum);
        psum = fmaf(f1, f1, psum);
        psum = fmaf(f2, f2, psum);
        psum = fmaf(f3, f3, psum);
    }
    #pragma unroll
    for (int off = 32; off > 0; off >>= 1)
        psum += __shfl_down(psum, off, 64);
    if (lane == 0) s_red[wv] = psum;
    __syncthreads();
    if (tid == 0) {
        const float b = (s_red[0] + s_red[1]) + (s_red[2] + s_red[3]);
        atomicAdd(loss, b * LOSS_SCALE);
    }
}

// Pass 2: exact fp32 re-resolution of flagged rows. One wave per list entry
// (grid-stride); lane scans 16 codes; 64-lane first-min reduce; corrects
// out-row and loss if the winner changed.
__global__ __launch_bounds__(256) void vq_pass2(
    const float* __restrict__ ze, const float* __restrict__ embs,
    const float* __restrict__ e2, float* __restrict__ out,
    float* __restrict__ loss, const unsigned* __restrict__ cnt,
    const unsigned* __restrict__ list, int listcap)
{
    const int tid  = threadIdx.x;
    const int lane = tid & 63;
    const int wave = blockIdx.x * 4 + (tid >> 6);
    const int nwaves = gridDim.x * 4;
    int n = (int)*cnt;
    if (n > listcap) n = listcap;

    for (int e = wave; e < n; e += nwaves) {
        const unsigned v = list[e];
        const int row = (int)(v >> 10);
        const int oldidx = (int)(v & 1023u);

        const float* zp = ze + (size_t)row * CDIM;
        float zm2[CDIM];
        #pragma unroll
        for (int d = 0; d < CDIM; d += 4) {
            const float4 t4 = *(const float4*)(zp + d);
            zm2[d + 0] = -2.0f * t4.x; zm2[d + 1] = -2.0f * t4.y;
            zm2[d + 2] = -2.0f * t4.z; zm2[d + 3] = -2.0f * t4.w;
        }
        float b = INFINITY; int bi = 0;
        const int c0 = lane * 16;
        for (int c = c0; c < c0 + 16; ++c) {
            const float* ep = embs + (size_t)c * CDIM;
            float a0 = e2[c], a1 = 0.0f, a2 = 0.0f, a3 = 0.0f;
            #pragma unroll
            for (int d = 0; d < CDIM; d += 4) {
                a0 = fmaf(zm2[d + 0], ep[d + 0], a0);
                a1 = fmaf(zm2[d + 1], ep[d + 1], a1);
                a2 = fmaf(zm2[d + 2], ep[d + 2], a2);
                a3 = fmaf(zm2[d + 3], ep[d + 3], a3);
            }
            const float dist = (a0 + a1) + (a2 + a3);
            if (dist < b) { b = dist; bi = c; }   // strict <, ascending c
        }
        #pragma unroll
        for (int off = 1; off < 64; off <<= 1) {
            const float ob = __shfl_xor(b, off, 64);
            const int   oi = __shfl_xor(bi, off, 64);
            if (ob < b || (ob == b && oi < bi)) { b = ob; bi = oi; }
        }
        if (bi != oldidx) {
            const float zd = ze[(size_t)row * CDIM + lane];
            const float en = embs[(size_t)bi * CDIM + lane];
            const float eo = embs[(size_t)oldidx * CDIM + lane];
            const float dn = en - zd, dd = eo - zd;
            float delta = fmaf(dn, dn, -dd * dd);
            #pragma unroll
            for (int off = 32; off > 0; off >>= 1)
                delta += __shfl_down(delta, off, 64);
            out[(size_t)row * CDIM + lane] = en;
            if (lane == 0) atomicAdd(loss, delta * LOSS_SCALE);
        }
    }
}

extern "C" void kernel_launch(void* const* d_in, const int* in_sizes, int n_in,
                              void* d_out, int out_size, void* d_ws, size_t ws_size,
                              hipStream_t stream) {
    const float* ze   = (const float*)d_in[0];   // [32,64,64,64] fp32
    const float* embs = (const float*)d_in[1];   // [1024,64] fp32
    float* out  = (float*)d_out;                 // zq_st (8388608 floats) then loss (1)
    float* loss = out + (out_size - 1);

    float*          e2   = (float*)d_ws;
    unsigned short* eh   = (unsigned short*)((char*)d_ws + WS_EH_OFF);
    unsigned*       cnt  = (unsigned*)((char*)d_ws + WS_CNT_OFF);
    unsigned*       list = (unsigned*)((char*)d_ws + WS_LIST_OFF);
    int listcap = 0;
    if (ws_size > WS_LIST_OFF + 4)
        listcap = (int)(((ws_size - WS_LIST_OFF) / 4 < (size_t)NROWS)
                            ? (ws_size - WS_LIST_OFF) / 4 : (size_t)NROWS);

    vq_zero<<<1, 1, 0, stream>>>(loss, cnt);
    vq_prep<<<NCODE / 256, 256, 0, stream>>>(embs, e2, eh);
    vq_pass1<<<NROWS / 128, 256, 0, stream>>>(ze, embs, e2, eh, out, loss,
                                              cnt, list, listcap);
    vq_pass2<<<256, 256, 0, stream>>>(ze, embs, e2, out, loss, cnt, list, listcap);
}